// Round 2
// 441.667 us; speedup vs baseline: 1.1347x; 1.1347x over previous
//
#include <hip/hip_runtime.h>
#include <math.h>

#define ROW_N 2048
#define KSEL 10
#define CAP 256

typedef float f32x4 __attribute__((ext_vector_type(4)));

// One block per row of 2048 f32; each thread owns 8 elements in registers:
//   r in [0,4): pos 4*tid + r          (first float4)
//   r in [4,8): pos 1024 + 4*tid + r-4 (second float4)
//
// Selection: threshold T = mu + 2.2*sigma (empirical row stats -> candidate
// count ~Binomial(2048,0.0139), mean ~29). Collect candidates as packed u64
// keys (ord_val<<16)|(2047-idx) -> exact top-10 by parallel rank among <=64
// candidates on wave 0. Tie-break (lowest index, per lax.top_k) exact via key.
// Rare retries: count<10 -> lower T by 0.5*sigma (P ~1e-3/row); count>64 ->
// serial slow path over <=256 candidates (P ~1e-9/row).
//
// Remaining softmax needs no mask: out = e_i / (total - topk_sum) * 0.1
// everywhere, then the 10 top-k positions are overwritten with
// 0.9*softmax(topk) after a barrier (barrier drains vmcnt -> ordering safe).
__global__ __launch_bounds__(256) void topk_softmax_kernel(
    const float* __restrict__ in, float* __restrict__ out)
{
    const int tid  = threadIdx.x;
    const int lane = tid & 63;
    const int wave = tid >> 6;
    const size_t base = (size_t)blockIdx.x * ROW_N;

    __shared__ unsigned long long s_cand[CAP];   // 2 KB
    __shared__ float s_sum[4], s_ssq[4], s_ws[4];
    __shared__ int   s_cc;
    __shared__ float s_tsum;
    __shared__ int   s_pi[KSEL];
    __shared__ float s_pv[KSEL];

    const float4 a = reinterpret_cast<const float4*>(in + base)[tid];
    const float4 b = reinterpret_cast<const float4*>(in + base)[tid + 256];
    float v[8] = {a.x, a.y, a.z, a.w, b.x, b.y, b.z, b.w};

    if (tid == 0) s_cc = 0;
    if (tid < KSEL) { s_pi[tid] = tid; s_pv[tid] = 0.f; }  // OOB guard for degenerate rows

    // block reduce: sum and sum-of-squares -> mean/std (stable threshold)
    float s = 0.f, q = 0.f;
    #pragma unroll
    for (int r = 0; r < 8; ++r) { s += v[r]; q = fmaf(v[r], v[r], q); }
    #pragma unroll
    for (int off = 32; off > 0; off >>= 1) {
        s += __shfl_down(s, off);
        q += __shfl_down(q, off);
    }
    if (lane == 0) { s_sum[wave] = s; s_ssq[wave] = q; }
    __syncthreads();

    const float S   = (s_sum[0] + s_sum[1]) + (s_sum[2] + s_sum[3]);
    const float Q2  = (s_ssq[0] + s_ssq[1]) + (s_ssq[2] + s_ssq[3]);
    const float mu  = S * (1.f / ROW_N);
    const float sig = sqrtf(fmaxf(Q2 * (1.f / ROW_N) - mu * mu, 1e-20f));
    const float shift = fmaf(4.f, sig, mu);        // shared exp shift frame
    float Tf = fmaf(2.2f, sig, mu);                // candidate threshold

    // exp of ALL elements in the shift frame + block sum.
    // rem_sum = total - sum(exp(top10)) -> no mask, no dependency on 10th value.
    float e[8]; float loc = 0.f;
    #pragma unroll
    for (int r = 0; r < 8; ++r) { e[r] = __expf(v[r] - shift); loc += e[r]; }
    #pragma unroll
    for (int off = 32; off > 0; off >>= 1) loc += __shfl_down(loc, off);
    if (lane == 0) s_ws[wave] = loc;

    auto collect = [&](float T) {
        #pragma unroll
        for (int r = 0; r < 8; ++r) {
            if (v[r] > T) {
                int idx = (r < 4) ? (4 * tid + r) : (1024 + 4 * tid + (r - 4));
                uint32_t u  = __float_as_uint(v[r]);
                uint32_t ov = u ^ ((uint32_t)((int32_t)u >> 31) | 0x80000000u);
                int pos = atomicAdd(&s_cc, 1);
                if (pos < CAP)
                    s_cand[pos] = ((unsigned long long)ov << 16) |
                                  (unsigned)(2047 - idx);
            }
        }
    };
    collect(Tf);
    __syncthreads();

    int C = s_cc;
    int tries = 0;
    while (C < KSEL && tries < 6) {      // rare: ~1e-3 of rows, usually 1 pass
        __syncthreads();                  // all threads done reading s_cc
        if (tid == 0) s_cc = 0;
        Tf -= 0.5f * sig;
        __syncthreads();                  // reset visible
        collect(Tf);
        __syncthreads();
        C = s_cc;
        ++tries;
    }

    if (wave == 0) {
        float myval; int myidx; int rank; bool valid;
        if (C <= 64) {
            // parallel rank-select: rank = #{keys > mine}; keys unique (idx).
            // Independent 64-shuffle chain (pipelined) vs 10 serial reduces.
            unsigned long long k0 = (lane < C) ? s_cand[lane] : 0ULL;
            rank = 0;
            #pragma unroll
            for (int j = 0; j < 64; ++j) {
                unsigned long long o = __shfl(k0, j);
                rank += (o > k0) ? 1 : 0;
            }
            uint32_t ovk  = (uint32_t)(k0 >> 16);
            uint32_t bits = ovk ^ ((ovk & 0x80000000u) ? 0x80000000u : 0xFFFFFFFFu);
            myval = __uint_as_float(bits);
            myidx = 2047 - (int)(k0 & 0xFFFFull);
            valid = (k0 != 0ULL);
        } else {
            // slow path (~never): serial exact top-10 over up to CAP keys
            int CC = C > CAP ? CAP : C;
            unsigned long long kk[4];
            #pragma unroll
            for (int j = 0; j < 4; ++j)
                kk[j] = (j * 64 + lane < CC) ? s_cand[j * 64 + lane] : 0ULL;
            unsigned long long mykey = 0;
            #pragma unroll
            for (int it = 0; it < KSEL; ++it) {
                unsigned long long bk = kk[0]; int bj = 0;
                #pragma unroll
                for (int j = 1; j < 4; ++j)
                    if (kk[j] > bk) { bk = kk[j]; bj = j; }
                unsigned long long wk = bk;
                #pragma unroll
                for (int off = 32; off > 0; off >>= 1) {
                    unsigned long long o = __shfl_down(wk, off);
                    if (o > wk) wk = o;
                }
                wk = __shfl(wk, 0);
                if (bk == wk) {
                    if      (bj == 0) kk[0] = 0;
                    else if (bj == 1) kk[1] = 0;
                    else if (bj == 2) kk[2] = 0;
                    else              kk[3] = 0;
                }
                if (lane == it) mykey = wk;
            }
            uint32_t ovk  = (uint32_t)(mykey >> 16);
            uint32_t bits = ovk ^ ((ovk & 0x80000000u) ? 0x80000000u : 0xFFFFFFFFu);
            myval = __uint_as_float(bits);
            myidx = 2047 - (int)(mykey & 0xFFFFull);
            rank  = lane;               // lanes 0..9 hold sorted top-10
            valid = (mykey != 0ULL);
        }
        // top-k softmax over ranks 0..9 (rank 0 = row max)
        unsigned long long m0 = __ballot(rank == 0);
        int l0 = __ffsll((unsigned long long)m0) - 1;
        float vmax = __shfl(myval, l0);
        float ee = (rank < KSEL && valid) ? __expf(myval - vmax) : 0.f;
        float ssum = ee;
        #pragma unroll
        for (int off = 32; off > 0; off >>= 1) ssum += __shfl_down(ssum, off);
        ssum = __shfl(ssum, 0);
        if (rank < KSEL && valid) { s_pi[rank] = myidx; s_pv[rank] = ee * (0.9f / ssum); }
        if (lane == 0) s_tsum = ssum * __expf(vmax - shift);  // top-10 mass in shift frame
    }
    __syncthreads();

    const float total   = (s_ws[0] + s_ws[1]) + (s_ws[2] + s_ws[3]);
    const float inv_rem = 0.1f / (total - s_tsum);

    f32x4 o0 = {e[0] * inv_rem, e[1] * inv_rem, e[2] * inv_rem, e[3] * inv_rem};
    f32x4 o1 = {e[4] * inv_rem, e[5] * inv_rem, e[6] * inv_rem, e[7] * inv_rem};
    __builtin_nontemporal_store(o0, reinterpret_cast<f32x4*>(out + base) + tid);
    __builtin_nontemporal_store(o1, reinterpret_cast<f32x4*>(out + base) + tid + 256);
    __syncthreads();                    // drains vmcnt -> stores complete
    if (tid < KSEL) out[base + s_pi[tid]] = s_pv[tid];   // patch top-k positions
}

extern "C" void kernel_launch(void* const* d_in, const int* in_sizes, int n_in,
                              void* d_out, int out_size, void* d_ws, size_t ws_size,
                              hipStream_t stream) {
    const float* logits = (const float*)d_in[0];
    float* out = (float*)d_out;
    const int rows = out_size / ROW_N;   // 2*8*2048 = 32768
    topk_softmax_kernel<<<dim3(rows), dim3(256), 0, stream>>>(logits, out);
}